// Round 3
// baseline (406.048 us; speedup 1.0000x reference)
//
#include <hip/hip_runtime.h>

// DIN attention layer: B=2048, L=200, E=128, H=64.  R3: occupancy + barriers.
// One WG (256 thr) per batch row. Keys live only in registers (MFMA A-frags,
// reused for weighted sum via shuffles). LDS 29KB, 3 barriers total,
// __launch_bounds__(256,3). Weight algebra precomputed in K0 (d_ws).

#define NB 2048
#define LE 128   // E
#define LH 64    // H
#define LL 200   // L

typedef short bf16x8 __attribute__((ext_vector_type(8)));
typedef float f32x4 __attribute__((ext_vector_type(4)));

__device__ __forceinline__ short f2bf(float f) {  // RNE float->bf16
  unsigned u = __float_as_uint(f);
  u += 0x7fffu + ((u >> 16) & 1u);
  return (short)(u >> 16);
}
__device__ __forceinline__ float bf2f(short h) {
  return __uint_as_float(((unsigned)(unsigned short)h) << 16);
}

struct __align__(16) SM {
  short wk[64 * 136];     // 17408 B: Wk[h][e], row stride 136 (bank-safe frags)
  short h1[4][16 * 72];   // 9216 B: per-wave h1 transpose; overlaid by redf
  float scores[208];      // 832 B
  int   smask[208];       // 832 B
  float biasp[4][64];     // 1024 B
};  // 29312 B -> LDS allows 5 WG/CU (VGPR caps at 3)

// ---- K0: b-independent weight prep into workspace ------------------------
// BD[h][e]=W1b-W1d ; Cq[h][e]=W1c ; AD[e][h]=W1a+W1d ; W2T[n][k] (bf16)
__global__ void k0_prep(const float* __restrict__ W1, const float* __restrict__ W2,
                        float* __restrict__ BD, float* __restrict__ Cq,
                        float* __restrict__ AD, short* __restrict__ W2T) {
  int idx = blockIdx.x * 256 + threadIdx.x;  // 32 blocks * 256 = 8192
  if (idx < 8192) {
    int h = idx >> 7, e = idx & 127;
    BD[idx] = W1[(128 + e) * LH + h] - W1[(384 + e) * LH + h];
    Cq[idx] = W1[(256 + e) * LH + h];
    int e2 = idx >> 6, h2 = idx & 63;
    AD[idx] = W1[e2 * LH + h2] + W1[(384 + e2) * LH + h2];
    if (idx < 4096) {
      int c = idx >> 6, k = idx & 63;
      W2T[idx] = f2bf(W2[k * LH + c]);
    }
  }
}

__global__ void __launch_bounds__(256, 3)
din_attn(const float* __restrict__ query, const float* __restrict__ keysg,
         const int* __restrict__ mask, const float* __restrict__ b1,
         const float* __restrict__ b2, const float* __restrict__ W3,
         const float* __restrict__ no_hist,
         const float* __restrict__ BD, const float* __restrict__ Cq,
         const float* __restrict__ AD, const short* __restrict__ W2T,
         float* __restrict__ out)
{
  __shared__ SM sm;
  const int b    = blockIdx.x;
  const int t    = threadIdx.x;
  const int lane = t & 63;
  const int wv   = t >> 6;
  const int col  = lane & 15;   // MFMA m/n index
  const int quad = lane >> 4;   // MFMA k-group

  const float* kb = keysg + (size_t)b * (LL * LE);

  // ---- prefetch first keys tile (mt = wv) so HBM streams from WG start
  float4 pre[8];
  {
    int row = wv * 16 + col;                 // < 64, always valid
    const float* rp = kb + row * LE;
    #pragma unroll
    for (int kt = 0; kt < 4; ++kt) {
      pre[2 * kt]     = *(const float4*)&rp[kt * 32 + quad * 8];
      pre[2 * kt + 1] = *(const float4*)&rp[kt * 32 + quad * 8 + 4];
    }
  }

  // ---- phase 0: smask, cooperative Wk build, bias1 partials (L2 traffic)
  if (t < 208) sm.smask[t] = (t < LL) ? mask[b * LL + t] : 0;

  {
    const int e0 = (t * 4) & 127;
    float4 qv = *(const float4*)&query[b * LE + e0];
    #pragma unroll
    for (int i = 0; i < 8; ++i) {
      int idx = t * 4 + i * 1024;
      int h = idx >> 7;
      float4 bd = *(const float4*)&BD[idx];
      float4 cq = *(const float4*)&Cq[idx];
      short w0 = f2bf(bd.x + qv.x * cq.x);
      short w1 = f2bf(bd.y + qv.y * cq.y);
      short w2 = f2bf(bd.z + qv.z * cq.z);
      short w3v = f2bf(bd.w + qv.w * cq.w);
      short4 wq = make_short4(w0, w1, w2, w3v);
      *(short4*)&sm.wk[h * 136 + e0] = wq;
    }
  }
  {  // bias1 partial: wave wv sums its e-quarter for all 64 h (h = lane)
    float acc = 0.f;
    const float* adp = &AD[(wv * 32) * LH + lane];
    const float* qp  = &query[b * LE + wv * 32];
    #pragma unroll 8
    for (int e = 0; e < 32; ++e)
      acc = fmaf(qp[e], adp[e * LH], acc);
    sm.biasp[wv][lane] = acc;
  }
  __syncthreads();  // BARRIER 1: wk, smask, biasp visible

  // ---- frags + per-lane scalars
  bf16x8 fB1[4][4];
  #pragma unroll
  for (int n = 0; n < 4; ++n)
    #pragma unroll
    for (int kt = 0; kt < 4; ++kt)
      fB1[n][kt] = *(const bf16x8*)&sm.wk[(n * 16 + col) * 136 + kt * 32 + quad * 8];

  bf16x8 fB2[4][2];
  #pragma unroll
  for (int n = 0; n < 4; ++n)
    #pragma unroll
    for (int k2 = 0; k2 < 2; ++k2)
      fB2[n][k2] = *(const bf16x8*)&W2T[(n * 16 + col) * 64 + k2 * 32 + quad * 8];

  float bias1r[4], b2r[4], w3r[4];
  #pragma unroll
  for (int n = 0; n < 4; ++n) {
    int h = n * 16 + col;
    bias1r[n] = b1[h] + sm.biasp[0][h] + sm.biasp[1][h] + sm.biasp[2][h] + sm.biasp[3][h];
    b2r[n] = b2[h];
    w3r[n] = W3[h];
  }

  // ---- main loop: wave wv owns tiles {wv, wv+4, wv+8} (+12 for wv==0).
  // Keys stay in registers (ak) for the weighted-sum phase. No barriers.
  bf16x8 ak[4][4];
  short* h1w = &sm.h1[wv][0];

  auto do_tile = [&](int mt, bf16x8 (&a)[4], const float4* preld) {
    int row = mt * 16 + col;
    int rowg = row < LL ? row : LL - 1;       // clamp only matters for mt==12
    const float* rp = kb + rowg * LE;
    #pragma unroll
    for (int kt = 0; kt < 4; ++kt) {
      float4 v0, v1;
      if (preld) { v0 = preld[2 * kt]; v1 = preld[2 * kt + 1]; }
      else {
        v0 = *(const float4*)&rp[kt * 32 + quad * 8];
        v1 = *(const float4*)&rp[kt * 32 + quad * 8 + 4];
      }
      bf16x8 av;
      av[0] = f2bf(v0.x); av[1] = f2bf(v0.y); av[2] = f2bf(v0.z); av[3] = f2bf(v0.w);
      av[4] = f2bf(v1.x); av[5] = f2bf(v1.y); av[6] = f2bf(v1.z); av[7] = f2bf(v1.w);
      a[kt] = av;
    }
    #pragma unroll
    for (int n = 0; n < 4; ++n) {
      f32x4 acc = {0.f, 0.f, 0.f, 0.f};
      #pragma unroll
      for (int kt = 0; kt < 4; ++kt)
        acc = __builtin_amdgcn_mfma_f32_16x16x32_bf16(a[kt], fB1[n][kt], acc, 0, 0, 0);
      #pragma unroll
      for (int i = 0; i < 4; ++i)  // C layout: row=quad*4+i, col
        h1w[(quad * 4 + i) * 72 + n * 16 + col] =
            f2bf(fmaxf(acc[i] + bias1r[n], 0.f));
    }
    bf16x8 a2[2];  // wave-local LDS transpose (compiler lgkmcnt only)
    #pragma unroll
    for (int k2 = 0; k2 < 2; ++k2)
      a2[k2] = *(const bf16x8*)&h1w[col * 72 + k2 * 32 + quad * 8];
    float p[4] = {0.f, 0.f, 0.f, 0.f};
    #pragma unroll
    for (int n = 0; n < 4; ++n) {
      f32x4 c2 = {0.f, 0.f, 0.f, 0.f};
      c2 = __builtin_amdgcn_mfma_f32_16x16x32_bf16(a2[0], fB2[n][0], c2, 0, 0, 0);
      c2 = __builtin_amdgcn_mfma_f32_16x16x32_bf16(a2[1], fB2[n][1], c2, 0, 0, 0);
      #pragma unroll
      for (int i = 0; i < 4; ++i)
        p[i] = fmaf(fmaxf(c2[i] + b2r[n], 0.f), w3r[n], p[i]);  // b3 dropped
    }
    #pragma unroll
    for (int i = 0; i < 4; ++i) {
      #pragma unroll
      for (int off = 1; off < 16; off <<= 1)
        p[i] += __shfl_xor(p[i], off);  // reduce over 16 cols
      if (col == 0) {
        int r = mt * 16 + quad * 4 + i;
        sm.scores[r] = sm.smask[r] ? p[i] : -3.0e38f;  // mask fused into score
      }
    }
  };

  do_tile(wv,     ak[0], pre);
  do_tile(wv + 4, ak[1], nullptr);
  do_tile(wv + 8, ak[2], nullptr);
  if (wv == 0) do_tile(12, ak[3], nullptr);
  __syncthreads();  // BARRIER 2: all 208 scores visible

  // ---- softmax: every wave reduces all 208 scores redundantly (identical
  // results, no cross-wave reduce, no extra barrier)
  float s0 = sm.scores[lane];
  float s1 = sm.scores[lane + 64];
  float s2 = sm.scores[lane + 128];
  float s3 = (lane < 16) ? sm.scores[lane + 192] : -3.0e38f;
  float M = fmaxf(fmaxf(s0, s1), fmaxf(s2, s3));
  #pragma unroll
  for (int off = 1; off < 64; off <<= 1) M = fmaxf(M, __shfl_xor(M, off));
  bool allpad = (M <= -1.0e38f);  // all slots masked
  float ex[4];
  ex[0] = __expf(s0 - M);
  ex[1] = __expf(s1 - M);
  ex[2] = __expf(s2 - M);
  ex[3] = (lane < 16) ? __expf(s3 - M) : 0.f;
  float Z = ex[0] + ex[1] + ex[2] + ex[3];
  #pragma unroll
  for (int off = 1; off < 64; off <<= 1) Z += __shfl_xor(Z, off);
  float rz = allpad ? 0.f : (1.f / Z);
  ex[0] *= rz; ex[1] *= rz; ex[2] *= rz; ex[3] *= rz;

  // attn for this lane's wsum rows (row = mt*16+col, holder lane = wv*16+col)
  float at0 = __shfl(ex[0], wv * 16 + col);   // mt = wv
  float at1 = __shfl(ex[1], wv * 16 + col);   // mt = wv+4
  float at2 = __shfl(ex[2], wv * 16 + col);   // mt = wv+8
  float at3 = __shfl(ex[3], col);             // mt = 12 (used by wv==0 only)

  // ---- weighted sum from register keys; per-wave partials into LDS
  float* redfw = (float*)&sm.h1[wv][0];  // 128 floats, wave-private (h1 dead)
  #pragma unroll
  for (int kt = 0; kt < 4; ++kt) {
    float acc8[8] = {0.f, 0.f, 0.f, 0.f, 0.f, 0.f, 0.f, 0.f};
    #pragma unroll
    for (int x = 0; x < 8; ++x) {
      acc8[x] = fmaf(at0, bf2f(ak[0][kt][x]), acc8[x]);
      acc8[x] = fmaf(at1, bf2f(ak[1][kt][x]), acc8[x]);
      acc8[x] = fmaf(at2, bf2f(ak[2][kt][x]), acc8[x]);
    }
    if (wv == 0) {
      #pragma unroll
      for (int x = 0; x < 8; ++x)
        acc8[x] = fmaf(at3, bf2f(ak[3][kt][x]), acc8[x]);
    }
    #pragma unroll
    for (int off = 1; off < 16; off <<= 1)
      #pragma unroll
      for (int x = 0; x < 8; ++x)
        acc8[x] += __shfl_xor(acc8[x], off);  // sum over 16 cols
    if (col == 0) {  // e = kt*32 + quad*8 + x
      *(float4*)&redfw[kt * 32 + quad * 8]     =
          make_float4(acc8[0], acc8[1], acc8[2], acc8[3]);
      *(float4*)&redfw[kt * 32 + quad * 8 + 4] =
          make_float4(acc8[4], acc8[5], acc8[6], acc8[7]);
    }
  }
  __syncthreads();  // BARRIER 3: per-wave partials visible

  if (t < LE) {
    const float* r0 = (const float*)&sm.h1[0][0];  // wave stride = 576 floats
    float s = r0[t] + r0[576 + t] + r0[1152 + t] + r0[1728 + t];
    if (allpad) s = no_hist[t];
    out[b * LE + t] = s;
  }
}

extern "C" void kernel_launch(void* const* d_in, const int* in_sizes, int n_in,
                              void* d_out, int out_size, void* d_ws, size_t ws_size,
                              hipStream_t stream) {
  (void)in_sizes; (void)n_in; (void)ws_size; (void)out_size;
  const float* query   = (const float*)d_in[0];
  const float* keysg   = (const float*)d_in[1];
  const int*   mask    = (const int*)d_in[2];
  const float* W1      = (const float*)d_in[3];
  const float* b1      = (const float*)d_in[4];
  const float* W2      = (const float*)d_in[5];
  const float* b2      = (const float*)d_in[6];
  const float* W3      = (const float*)d_in[7];
  // d_in[8] = b3: unused (softmax shift-invariant)
  const float* no_hist = (const float*)d_in[9];

  float* BD  = (float*)d_ws;            // 8192 f32
  float* Cq  = BD + 8192;               // 8192 f32
  float* AD  = Cq + 8192;               // 8192 f32
  short* W2T = (short*)(AD + 8192);     // 4096 bf16

  k0_prep<<<32, 256, 0, stream>>>(W1, W2, BD, Cq, AD, W2T);
  din_attn<<<NB, 256, 0, stream>>>(query, keysg, mask, b1, b2, W3, no_hist,
                                   BD, Cq, AD, W2T, (float*)d_out);
}